// Round 6
// baseline (302.870 us; speedup 1.0000x reference)
//
#include <hip/hip_runtime.h>

#define BATCH 16384
#define NUM   512
#define CONS  512
#define ROWS  4                      // rows per wave/block (2 row-pairs)
#define ZOFF  (NUM*8)                // 4096: 16 zero dummy atoms x 8B
#define OOFF  (NUM*8 + 128)          // 4224: 16 one dummy atoms x 8B
#define LDSB  (NUM*8 + 256)          // 4352 B
#define NPAIR 260                    // 256 real pairs + 4 pad pairs
#define NPAD  (2*NPAIR)              // 520 constraint records
#define RSTR  148                    // record words per constraint

typedef _Float16 h2 __attribute__((ext_vector_type(2)));
static __device__ __forceinline__ h2 u2h(unsigned u){ return __builtin_bit_cast(h2,u); }
static __device__ __forceinline__ unsigned h2u(h2 h){ return __builtin_bit_cast(unsigned,h); }
static __device__ __forceinline__ h2 hmax2(h2 a,h2 b){ return __builtin_elementwise_max(a,b); }
static __device__ __forceinline__ h2 hmin2(h2 a,h2 b){ return __builtin_elementwise_min(a,b); }
template<int C>
static __device__ __forceinline__ h2 dppmax(h2 x) {
  unsigned v = (unsigned)__builtin_amdgcn_mov_dpp((int)h2u(x), C, 0xF, 0xF, true);
  return hmax2(x, u2h(v));
}
static __device__ __forceinline__ h2 bmask(unsigned mh, int bit) {
  // all-ones h2 if bit set, else 0
  return u2h((unsigned)(((int)(mh << (31 - bit))) >> 31));
}
static __device__ __forceinline__ h2 swap32pair(h2 x, bool hi) {
  // value of the same register in the other wave-half (lane ^ 32).
  // permlane32_swap(vdst,src): vdst[32..63] <-> src[0..31]. With both = x:
  //   r[0] = x_lo broadcast into both halves, r[1] = x_hi broadcast.
  // Other-half value: hi lanes need x_lo = r[0]; lo lanes need x_hi = r[1].
  auto r = __builtin_amdgcn_permlane32_swap((int)h2u(x), (int)h2u(x), false, false);
  return u2h((unsigned)(hi ? r[0] : r[1]));
}

// record (RSTR words per c): two row-pair copies (pr = 0,4 pre-added):
//   copy*65 + [0..15]  = N slots g | g+16      (packed u16 LDS byte addrs)
//   copy*65 + [16..31] = N slots 32+g | 48+g
//   copy*65 + [32..47] = P slots g | g+16
//   copy*65 + [48..63] = P slots 32+g | 48+g
//   copy*65 + 64       = (ho+pr) | fl<<16
// [130..137] exN (raw addr), [138..145] exP, [146..147] pad
// fl: 0 sign | 1-4 N1 P1 N2 P2 | 5-6 Rcode(0..3) | 7-9 exN | 10-12 exP
//     | 13 N3 | 14 P3 | 15 SKIP-write (pad, or even cons whose head == next head)
__global__ __launch_bounds__(64) void prep_kernel(
    const float* __restrict__ pos, const float* __restrict__ neg,
    const int* __restrict__ head_atom, const int* __restrict__ head_sign,
    unsigned* __restrict__ ents) {
  int c = blockIdx.x, lane = threadIdx.x;
  unsigned* rec = ents + (size_t)c * RSTR;
  __shared__ unsigned short slotN[64], slotP[64];
  __shared__ unsigned char  usedN[64], usedP[64];
  __shared__ unsigned short spillN[16][12], spillP[16][12];
  __shared__ unsigned char  spnN[16], spnP[16];
  __shared__ unsigned short exN[8], exP[8];
  __shared__ int exn, exp_;
  slotN[lane] = (unsigned short)(ZOFF + (lane & 15) * 8);   // class-matched dummies
  slotP[lane] = (unsigned short)(OOFF + (lane & 15) * 8);
  usedN[lane] = 0; usedP[lane] = 0;
  if (lane < 8)  { exN[lane] = ZOFF; exP[lane] = OOFF; }
  if (lane < 16) { spnN[lane] = 0;  spnP[lane] = 0; }
  if (lane == 0) { exn = 0; exp_ = 0; }
  __syncthreads();

  unsigned fl = 0, ho = ZOFF;
  if (c < CONS) {
    int hp1 = (c >= 1) ? head_atom[c-1] : -1;
    int hp2 = (c >= 2) ? head_atom[c-2] : -1;
    int hp3 = ((c & 1) && c >= 3) ? head_atom[c-3] : -1;   // dist-3 only for odd c
    bool fN1=false,fP1=false,fN2=false,fP2=false,fN3=false,fP3=false;
    const int myclass = lane & 15;                          // == atom & 15 for all k
    const unsigned long long clsmask = 0x0001000100010001ull << myclass;
    const unsigned long long lt = (1ull << lane) - 1ull;
    int cntN = 0, cntP = 0;
    for (int k = 0; k < NUM/64; ++k) {
      int a = k*64 + lane;
      bool ln = neg[(size_t)c*NUM + a] != 0.f;
      bool lp = pos[(size_t)c*NUM + a] != 0.f;
      bool i1 = (a == hp1);
      bool i2 = (a == hp2) && !i1;
      bool i3 = (a == hp3) && !i1 && (a != hp2);
      fN1 |= __ballot(ln && i1) != 0ull; fP1 |= __ballot(lp && i1) != 0ull;
      fN2 |= __ballot(ln && i2) != 0ull; fP2 |= __ballot(lp && i2) != 0ull;
      fN3 |= __ballot(ln && i3) != 0ull; fP3 |= __ballot(lp && i3) != 0ull;
      bool kn = ln && !i1 && !i2 && !i3;
      bool kp = lp && !i1 && !i2 && !i3;
      unsigned long long mn = __ballot(kn) & clsmask;
      unsigned long long mp = __ballot(kp) & clsmask;
      if (kn) {                                  // parallel residue-16 dealing
        int rr = cntN + (int)__popcll(mn & lt);
        if (rr < 4) { slotN[rr*16+myclass] = (unsigned short)(a*8); usedN[rr*16+myclass] = 1; }
        else if (rr < 16) spillN[myclass][rr-4] = (unsigned short)(a*8);
      }
      if (kp) {
        int rr = cntP + (int)__popcll(mp & lt);
        if (rr < 4) { slotP[rr*16+myclass] = (unsigned short)(a*8); usedP[rr*16+myclass] = 1; }
        else if (rr < 16) spillP[myclass][rr-4] = (unsigned short)(a*8);
      }
      cntN += (int)__popcll(mn); cntP += (int)__popcll(mp);
    }
    if (lane < 16) {
      int sn = cntN - 4; if (sn < 0) sn = 0; if (sn > 12) sn = 12;
      int sp = cntP - 4; if (sp < 0) sp = 0; if (sp > 12) sp = 12;
      spnN[lane] = (unsigned char)sn; spnP[lane] = (unsigned char)sp;
    }
    __syncthreads();
    if (lane < 2) {                              // spill placement (serial, tiny)
      bool isP = lane == 1;
      unsigned short* slot = isP ? slotP : slotN;
      unsigned char*  used = isP ? usedP : usedN;
      unsigned char*  spn  = isP ? spnP  : spnN;
      unsigned short* exb  = isP ? exP   : exN;
      int e = 0, scan = 0;
      for (int r = 0; r < 16; ++r) {
        int ns = spn[r];
        for (int k = 0; k < ns; ++k) {
          unsigned short v = isP ? spillP[r][k] : spillN[r][k];
          while (scan < 64 && used[scan]) ++scan;
          if (scan < 64) { slot[scan] = v; used[scan] = 1; }
          else if (e < 7) exb[e++] = v;
        }
      }
      if (isP) exp_ = e; else exn = e;
    }
    __syncthreads();
    int hc = head_atom[c];
    fl = (head_sign[c] ? 1u : 0u)
       | (fN1?2u:0u) | (fP1?4u:0u) | (fN2?8u:0u) | (fP2?16u:0u);
    unsigned rcode = (hc==hp1) ? 1u : (hc==hp2) ? 2u : (hc==hp3) ? 3u : 0u;
    fl |= rcode << 5;
    fl |= ((unsigned)exn) << 7;
    fl |= ((unsigned)exp_) << 10;
    if (fN3) fl |= 1u << 13;
    if (fP3) fl |= 1u << 14;
    // same-head-within-pair: both halves would ds_write the same address in the
    // same issue (undefined winner). Suppress the even write; the odd core's
    // rcode=1 redirect (prev2 = upd_even) already chains the even update, and
    // the odd write is the sequentially-correct final value.
    if (!(c & 1) && (c + 1) < CONS && head_atom[c+1] == hc) fl |= 0x8000u;
    ho = (unsigned)hc * 8u;
  } else {
    fl = 0x8000u;                                // SKIP pad record
  }

  for (int t = lane; t < RSTR; t += 64) {
    unsigned v;
    if (t < 130) {
      int copy = (t >= 65) ? 1 : 0;
      int u = t - copy*65;
      unsigned pr = (unsigned)copy * 4u;
      if (u == 64) v = (ho + pr) | (fl << 16);
      else {
        int gg = u & 15, blk = u >> 4;
        const unsigned short* arr = (blk >= 2) ? slotP : slotN;
        int base = (blk & 1) * 32;
        v = ((unsigned)arr[base+gg] + pr) | ((((unsigned)arr[base+16+gg]) + pr) << 16);
      }
    } else if (t < 138) v = exN[t-130];
    else if (t < 146) v = exP[t-138];
    else v = 0;
    rec[t] = v;
  }
}

struct PENT { unsigned r0, r1, r2, r3, rm; };
struct RDv  { h2 n0,n1,n2,n3,p0,p1,p2,p3,pv; unsigned mh; };
struct ST   { h2 bp, pv; unsigned mh, su; };

static __device__ __forceinline__ PENT pld(const unsigned* ents, int p, int lo, int lm) {
  const unsigned* bp = ents + (size_t)(2*p) * RSTR;
  PENT e;
  e.r0 = bp[lo]; e.r1 = bp[lo+16]; e.r2 = bp[lo+32]; e.r3 = bp[lo+48]; e.rm = bp[lm];
  return e;
}
static __device__ __forceinline__ void issue(const PENT& E, const char* Pb, RDv& R) {
  R.n0 = *(const h2*)(Pb + (E.r0 & 0xFFFFu));
  R.n1 = *(const h2*)(Pb + (E.r0 >> 16));
  R.n2 = *(const h2*)(Pb + (E.r1 & 0xFFFFu));
  R.n3 = *(const h2*)(Pb + (E.r1 >> 16));
  R.p0 = *(const h2*)(Pb + (E.r2 & 0xFFFFu));
  R.p1 = *(const h2*)(Pb + (E.r2 >> 16));
  R.p2 = *(const h2*)(Pb + (E.r3 & 0xFFFFu));
  R.p3 = *(const h2*)(Pb + (E.r3 >> 16));
  R.pv = *(const h2*)(Pb + (E.rm & 0xFFFFu));
  R.mh = E.rm;
}
static __device__ __forceinline__ void comb(const RDv& R, const unsigned* __restrict__ ents,
    int p, int half, unsigned pr4b, const char* Pb, ST& S) {
  h2 aN = hmax2(hmax2(R.n0,R.n1), hmax2(R.n2,R.n3));
  h2 aP = hmin2(hmin2(R.p0,R.p1), hmin2(R.p2,R.p3));
  unsigned s0 = (unsigned)__builtin_amdgcn_readfirstlane((int)R.mh);
  unsigned s1 = (unsigned)__builtin_amdgcn_readlane((int)R.mh, 32);
  unsigned su = s0 | s1;
  if (su & 0x1F800000u) {                        // extras tail (essentially never)
    unsigned xa = (s0>>23)&7u, xb = (s1>>23)&7u; unsigned xn = xa>xb?xa:xb;
    unsigned ya = (s0>>26)&7u, yb = (s1>>26)&7u; unsigned xp = ya>yb?ya:yb;
    const unsigned* rp_ = ents + (size_t)(2*p + half) * RSTR;
    for (unsigned j = 0; j < xn; ++j) aN = hmax2(aN, *(const h2*)(Pb + (rp_[130+j] + pr4b)));
    for (unsigned j = 0; j < xp; ++j) aP = hmin2(aP, *(const h2*)(Pb + (rp_[138+j] + pr4b)));
  }
  const h2 one2 = {(_Float16)1.f, (_Float16)1.f};
  h2 b = hmax2(aN, one2 - aP);
  // reduce over the 16 slot-lanes of this DPP row ({half, r2} group)
  b = dppmax<0xB1>(b);      // quad_perm xor1
  b = dppmax<0x4E>(b);      // quad_perm xor2
  b = dppmax<0x141>(b);     // row_half_mirror
  b = dppmax<0x140>(b);     // row_mirror
  S.bp = b; S.pv = R.pv; S.mh = R.mh; S.su = su;
}
static __device__ __forceinline__ void fin(const ST& S, h2& u1, h2& u2,
    char* Pb, bool hi32, bool wl) {
  const h2 one2 = {(_Float16)1.f, (_Float16)1.f};
  unsigned mh = S.mh, su = S.su;
  bool pbr = (su & 0x601E0000u) != 0;            // any body dep within window
  bool rbr = (su & 0x00600000u) != 0;            // any head redirect
  // core 1: valid for the even constraint (half0), deps (u1, u2)
  h2 b1 = S.bp;
  if (pbr) {
    b1 = hmax2(b1, u2h(h2u(u1)        & h2u(bmask(mh,17))));
    b1 = hmax2(b1, u2h(h2u(one2 - u1) & h2u(bmask(mh,18))));
    b1 = hmax2(b1, u2h(h2u(u2)        & h2u(bmask(mh,19))));
    b1 = hmax2(b1, u2h(h2u(one2 - u2) & h2u(bmask(mh,20))));
  }
  h2 prev1 = S.pv;
  if (rbr) {
    unsigned code = (mh >> 21) & 3u;
    prev1 = (code == 1u) ? u1 : prev1;
    prev1 = (code == 2u) ? u2 : prev1;
  }
  h2 ms = bmask(mh,16);
  h2 t1; { h2 hi = hmax2(prev1, one2 - b1); h2 lo = hmin2(prev1, b1);
           t1 = u2h((h2u(hi)&h2u(ms)) | (h2u(lo)&~h2u(ms))); }
  h2 upd = t1;
  if (pbr | rbr) {
    // core 2: valid for the odd constraint (half1), deps (upd(c), u1, u2)
    h2 x1 = swap32pair(t1, hi32);                // half1 <- upd(even cons)
    h2 b2 = S.bp;
    b2 = hmax2(b2, u2h(h2u(x1)        & h2u(bmask(mh,17))));
    b2 = hmax2(b2, u2h(h2u(one2 - x1) & h2u(bmask(mh,18))));
    b2 = hmax2(b2, u2h(h2u(u1)        & h2u(bmask(mh,19))));
    b2 = hmax2(b2, u2h(h2u(one2 - u1) & h2u(bmask(mh,20))));
    b2 = hmax2(b2, u2h(h2u(u2)        & h2u(bmask(mh,29))));
    b2 = hmax2(b2, u2h(h2u(one2 - u2) & h2u(bmask(mh,30))));
    h2 prev2 = S.pv;
    if (rbr) {
      unsigned code = (mh >> 21) & 3u;
      prev2 = (code == 1u) ? x1 : prev2;
      prev2 = (code == 2u) ? u1 : prev2;
      prev2 = (code == 3u) ? u2 : prev2;
    }
    h2 t2; { h2 hi = hmax2(prev2, one2 - b2); h2 lo = hmin2(prev2, b2);
             t2 = u2h((h2u(hi)&h2u(ms)) | (h2u(lo)&~h2u(ms))); }
    upd = hi32 ? t2 : t1;
  }
  if (wl && !(mh & 0x80000000u))
    *(h2*)(Pb + (mh & 0xFFFFu)) = upd;
  h2 sw = swap32pair(upd, hi32);
  u2 = hi32 ? sw  : upd;                         // upd(even cons) everywhere
  u1 = hi32 ? upd : sw;                          // upd(odd cons) everywhere
}

__global__ __launch_bounds__(64, 4) void solve_kernel(
    const float* __restrict__ preds,
    const unsigned* __restrict__ ents,
    float* __restrict__ out) {
  __shared__ char Pb[LDSB];
  const int lane = threadIdx.x;
  // lanes: g = lane&15 (slot-lane), r2 = (lane>>4)&1 (row-pair), half = lane>>5
  // half 0 processes even constraint of the pair, half 1 the odd one.
  // bank = 2*(atom&15) + r2 -> each half-wave covers 32 distinct banks.
  const int g    = lane & 15;
  const int r2i  = (lane >> 4) & 1;
  const int half = lane >> 5;
  const bool hi32 = half != 0;
  const bool wl   = (lane & 15) == 0;            // lanes 0,16,32,48 write
  const unsigned pr4b = (unsigned)r2i * 4u;
  const int lo = half*RSTR + r2i*65 + g;
  const int lm = half*RSTR + r2i*65 + 64;
  const size_t row0 = (size_t)blockIdx.x * ROWS;
  const int rp = lane >> 5, col = lane & 31;     // staging mapping

  if (lane < 32) *(unsigned*)(Pb + ZOFF + lane*4) = 0u;               // zero atoms
  else           *(unsigned*)(Pb + OOFF + (lane-32)*4) = 0x3C003C00u; // one atoms

  // stage in: [atom][4 rows] fp16, 8B/atom
  for (int i = 0; i < 8; ++i) {
    int a = i*64 + col*2;
    float2 v0 = *(const float2*)(preds + (row0 + 2*rp)     * NUM + a);
    float2 v1 = *(const float2*)(preds + (row0 + 2*rp + 1) * NUM + a);
    h2 w0 = {(_Float16)v0.x, (_Float16)v1.x};
    h2 w1 = {(_Float16)v0.y, (_Float16)v1.y};
    *(h2*)(Pb + a*8 + rp*4) = w0;
    *(h2*)(Pb + (a+1)*8 + rp*4) = w1;
  }
  __syncthreads();

  PENT A = pld(ents, 0, lo, lm), B = pld(ents, 1, lo, lm);
  PENT C = pld(ents, 2, lo, lm), D = pld(ents, 3, lo, lm);
  RDv Ra, Rb; ST S;
  issue(A, Pb, Ra);
  h2 u1 = (h2)0.0f, u2 = (h2)0.0f;

  #pragma unroll 1
  for (int q = 0; q < 256; q += 4) {             // 4 pairs = 8 constraints per iter
    issue(B, Pb, Rb);
    A = pld(ents, q+4, lo, lm);
    comb(Ra, ents, q,   half, pr4b, Pb, S); fin(S, u1, u2, Pb, hi32, wl);
    issue(C, Pb, Ra);
    B = pld(ents, q+5, lo, lm);
    comb(Rb, ents, q+1, half, pr4b, Pb, S); fin(S, u1, u2, Pb, hi32, wl);
    issue(D, Pb, Rb);
    C = pld(ents, q+6, lo, lm);
    comb(Ra, ents, q+2, half, pr4b, Pb, S); fin(S, u1, u2, Pb, hi32, wl);
    issue(A, Pb, Ra);
    D = pld(ents, q+7, lo, lm);
    comb(Rb, ents, q+3, half, pr4b, Pb, S); fin(S, u1, u2, Pb, hi32, wl);
  }

  __syncthreads();
  for (int i = 0; i < 8; ++i) {
    int a = i*64 + col*2;
    h2 w0 = *(const h2*)(Pb + a*8 + rp*4);
    h2 w1 = *(const h2*)(Pb + (a+1)*8 + rp*4);
    float2 v0 = {(float)w0.x, (float)w1.x};
    float2 v1 = {(float)w0.y, (float)w1.y};
    *(float2*)(out + (row0 + 2*rp)     * NUM + a) = v0;
    *(float2*)(out + (row0 + 2*rp + 1) * NUM + a) = v1;
  }
}

extern "C" void kernel_launch(void* const* d_in, const int* in_sizes, int n_in,
                              void* d_out, int out_size, void* d_ws, size_t ws_size,
                              hipStream_t stream) {
  (void)in_sizes; (void)n_in; (void)out_size; (void)ws_size;
  const float* preds     = (const float*)d_in[0];
  const float* pos       = (const float*)d_in[1];
  const float* neg       = (const float*)d_in[2];
  const int*   head_atom = (const int*)d_in[3];
  const int*   head_sign = (const int*)d_in[4];

  unsigned* ents = (unsigned*)d_ws;      // NPAD * RSTR * 4 ≈ 308 KB

  prep_kernel<<<NPAD, 64, 0, stream>>>(pos, neg, head_atom, head_sign, ents);
  solve_kernel<<<BATCH / ROWS, 64, 0, stream>>>(preds, ents, (float*)d_out);
}

// Round 10
// 285.018 us; speedup vs baseline: 1.0626x; 1.0626x over previous
//
#include <hip/hip_runtime.h>

#define BATCH 16384
#define NUM   512
#define CONS  512
#define ROWS  8                     // rows per wave/block
#define ZOFF  (NUM*16)              // 8192: 8 zero dummy atoms x 16B
#define OOFF  (NUM*16 + 128)        // 8320: 8 one dummy atoms x 16B
#define LDSB  (NUM*16 + 256)        // 8448 B
#define NPAD  520                   // 512 real + 8 pad records (pipeline depth)
#define RSTR  84                    // record words per constraint

typedef _Float16 h2 __attribute__((ext_vector_type(2)));
static __device__ __forceinline__ h2 u2h(unsigned u){ return __builtin_bit_cast(h2,u); }
static __device__ __forceinline__ unsigned h2u(h2 h){ return __builtin_bit_cast(unsigned,h); }
static __device__ __forceinline__ h2 hmax2(h2 a,h2 b){ return __builtin_elementwise_max(a,b); }
static __device__ __forceinline__ h2 hmin2(h2 a,h2 b){ return __builtin_elementwise_min(a,b); }
template<int C>
static __device__ __forceinline__ h2 dppmax(h2 x) {
  unsigned v = (unsigned)__builtin_amdgcn_mov_dpp((int)h2u(x), C, 0xF, 0xF, true);
  return hmax2(x, u2h(v));
}

// record (RSTR words per c):
// [0..15]=N steps(0,1) packed u16 pairs by g; [16..31]=N steps(2,3);
// [32..47]=P steps(0,1); [48..63]=P steps(2,3); [64]= ho | fl<<16;
// [65..72]=N extras; [73..80]=P extras; [81..83]=pad.
// fl: 0 sign |1 N1 |2 P1 |3 N2 |4 P2 |5 PR1 |6 PR2 |7-10 exN |11-14 exP |15 SKIP
__global__ __launch_bounds__(64) void prep_kernel(
    const float* __restrict__ pos, const float* __restrict__ neg,
    const int* __restrict__ head_atom, const int* __restrict__ head_sign,
    unsigned* __restrict__ ents) {
  int c = blockIdx.x, lane = threadIdx.x;
  unsigned* rec = ents + (size_t)c * RSTR;
  __shared__ unsigned short slotN[64], slotP[64];
  __shared__ unsigned char  usedN[64], usedP[64];
  __shared__ unsigned short spillN[8][12], spillP[8][12];
  __shared__ unsigned char  spnN[8], spnP[8];
  __shared__ unsigned short exN[8], exP[8];
  __shared__ int exn, exp_;
  slotN[lane] = (unsigned short)(ZOFF + (lane & 7) * 16);   // residue-matched dummies
  slotP[lane] = (unsigned short)(OOFF + (lane & 7) * 16);
  usedN[lane] = 0; usedP[lane] = 0;
  if (lane < 8) { exN[lane] = ZOFF; exP[lane] = OOFF; spnN[lane] = 0; spnP[lane] = 0; }
  if (lane == 0) { exn = 0; exp_ = 0; }
  __syncthreads();

  unsigned fl = 0, ho = ZOFF;
  if (c < CONS) {
    int hp1 = (c >= 1) ? head_atom[c-1] : -1;
    int hp2 = (c >= 2) ? head_atom[c-2] : -1;
    bool fN1=false, fP1=false, fN2=false, fP2=false;
    const int res = lane & 7;                  // == atom & 7 for every k
    const unsigned long long clsmask = 0x0101010101010101ull << res;
    const unsigned long long lt = (1ull << lane) - 1ull;
    int cntN = 0, cntP = 0;
    for (int k = 0; k < NUM/64; ++k) {
      int a = k*64 + lane;
      bool ln = neg[(size_t)c*NUM + a] != 0.f;
      bool lp = pos[(size_t)c*NUM + a] != 0.f;
      bool i1 = (a == hp1);
      bool i2 = (a == hp2) && !i1;             // latest-update priority on dup heads
      fN1 |= __ballot(ln && i1) != 0ull; fP1 |= __ballot(lp && i1) != 0ull;
      fN2 |= __ballot(ln && i2) != 0ull; fP2 |= __ballot(lp && i2) != 0ull;
      bool kn = ln && !i1 && !i2;
      bool kp = lp && !i1 && !i2;
      unsigned long long mn = __ballot(kn) & clsmask;
      unsigned long long mp = __ballot(kp) & clsmask;
      if (kn) {                                // parallel residue-8 dealing
        int rr = cntN + (int)__popcll(mn & lt);
        if (rr < 8) { slotN[rr*8+res] = (unsigned short)(a*16); usedN[rr*8+res] = 1; }
        else if (rr < 20) spillN[res][rr-8] = (unsigned short)(a*16);
      }
      if (kp) {
        int rr = cntP + (int)__popcll(mp & lt);
        if (rr < 8) { slotP[rr*8+res] = (unsigned short)(a*16); usedP[rr*8+res] = 1; }
        else if (rr < 20) spillP[res][rr-8] = (unsigned short)(a*16);
      }
      cntN += (int)__popcll(mn); cntP += (int)__popcll(mp);
    }
    if (lane < 8) {                            // lane == residue here
      int sn = cntN - 8; if (sn < 0) sn = 0; if (sn > 12) sn = 12;
      int sp = cntP - 8; if (sp < 0) sp = 0; if (sp > 12) sp = 12;
      spnN[lane] = (unsigned char)sn; spnP[lane] = (unsigned char)sp;
    }
    __syncthreads();
    if (lane < 2) {                            // spill placement (serial, tiny)
      bool isP = lane == 1;
      unsigned short* slot = isP ? slotP : slotN;
      unsigned char*  used = isP ? usedP : usedN;
      unsigned char*  spn  = isP ? spnP  : spnN;
      unsigned short* exb  = isP ? exP   : exN;
      int e = 0, scan = 0;
      for (int r = 0; r < 8; ++r) {
        int ns = spn[r];
        for (int k = 0; k < ns; ++k) {
          unsigned short v = isP ? spillP[r][k] : spillN[r][k];
          while (scan < 64 && used[scan]) ++scan;
          if (scan < 64) { slot[scan] = v; used[scan] = 1; }
          else if (e < 8) exb[e++] = v;
        }
      }
      if (isP) exp_ = e; else exn = e;
    }
    __syncthreads();
    int hc = head_atom[c];
    fl = (head_sign[c] ? 1u : 0u)
       | (fN1?2u:0u) | (fP1?4u:0u) | (fN2?8u:0u) | (fP2?16u:0u);
    if (hc == hp1) fl |= 32u; else if (hc == hp2) fl |= 64u;
    fl |= ((unsigned)exn << 7) | ((unsigned)exp_ << 11);
    ho = (unsigned)hc * 16u;
  } else {
    fl = 0x8000u;                              // SKIP pad record
  }

  for (int t = lane; t < RSTR; t += 64) {
    unsigned v;
    if (t < 32) {
      int jp = t >> 4, gg = t & 15;
      v = (unsigned)slotN[32*jp + gg] | ((unsigned)slotN[32*jp + 16 + gg] << 16);
    } else if (t < 64) {
      int tp = t - 32, jp = tp >> 4, gg = tp & 15;
      v = (unsigned)slotP[32*jp + gg] | ((unsigned)slotP[32*jp + 16 + gg] << 16);
    } else if (t == 64) v = ho | (fl << 16);
    else if (t < 73) v = exN[t - 65];
    else if (t < 81) v = exP[t - 73];
    else v = 0;
    rec[t] = v;
  }
}

struct ENT { unsigned w0, w1, w2, w3, mh; };
struct RDv { h2 n0,n1,n2,n3,p0,p1,p2,p3,pv; unsigned mh; };
struct ST  { h2 braw, prevraw; unsigned ho, flu; };

static __device__ __forceinline__ ENT ldent(const unsigned* ents, int c, int g) {
  const unsigned* rec = ents + (size_t)c * RSTR;
  ENT e;
  e.w0 = rec[g]; e.w1 = rec[16+g]; e.w2 = rec[32+g]; e.w3 = rec[48+g];
  e.mh = rec[64];
  return e;
}
static __device__ __forceinline__ void issue_reads(const ENT& E, const char* Pb,
                                                   unsigned pr4, RDv& R) {
  R.n0 = *(const h2*)(Pb + ((E.w0 & 0xFFFFu) + pr4));
  R.n1 = *(const h2*)(Pb + ((E.w0 >> 16)     + pr4));
  R.n2 = *(const h2*)(Pb + ((E.w1 & 0xFFFFu) + pr4));
  R.n3 = *(const h2*)(Pb + ((E.w1 >> 16)     + pr4));
  R.p0 = *(const h2*)(Pb + ((E.w2 & 0xFFFFu) + pr4));
  R.p1 = *(const h2*)(Pb + ((E.w2 >> 16)     + pr4));
  R.p2 = *(const h2*)(Pb + ((E.w3 & 0xFFFFu) + pr4));
  R.p3 = *(const h2*)(Pb + ((E.w3 >> 16)     + pr4));
  R.pv = *(const h2*)(Pb + ((E.mh & 0xFFFFu) + pr4));
  R.mh = E.mh;
}
static __device__ __forceinline__ void combine(const RDv& R, const unsigned* ents,
                                               int c, const char* Pb, unsigned pr4, ST& S) {
  h2 aN = hmax2(hmax2(R.n0, R.n1), hmax2(R.n2, R.n3));
  h2 aP = hmin2(hmin2(R.p0, R.p1), hmin2(R.p2, R.p3));
  unsigned flu = ((unsigned)__builtin_amdgcn_readfirstlane((int)R.mh)) >> 16;
  if (flu & 0x7F80u) {                        // rare extras tail (uniform)
    const unsigned* rec = ents + (size_t)c * RSTR;
    unsigned xn = (flu >> 7) & 15u, xp = (flu >> 11) & 15u;
    for (unsigned j = 0; j < xn; ++j) aN = hmax2(aN, *(const h2*)(Pb + (rec[65+j] + pr4)));
    for (unsigned j = 0; j < xp; ++j) aP = hmin2(aP, *(const h2*)(Pb + (rec[73+j] + pr4)));
  }
  const h2 one2 = {(_Float16)1.f, (_Float16)1.f};
  h2 bp = hmax2(aN, one2 - aP);               // >= 0 by construction
  // reduce across the group's 16 slot-lanes: 8 within this half-wave
  // (lanes (l&~7)..(l|7), all same r2), then across halves via permlane32_swap.
  bp = dppmax<0xB1>(bp);                      // quad_perm xor1
  bp = dppmax<0x4E>(bp);                      // quad_perm xor2
  bp = dppmax<0x141>(bp);                     // row_half_mirror
  {
    auto sw = __builtin_amdgcn_permlane32_swap((int)h2u(bp), (int)h2u(bp), false, false);
    bp = hmax2(u2h((unsigned)sw[0]), u2h((unsigned)sw[1]));   // orientation-insensitive
  }
  S.braw = bp; S.prevraw = R.pv; S.ho = R.mh & 0xFFFFu; S.flu = flu;
}
static __device__ __forceinline__ h2 finalize(const ST& S, h2 up1, h2 up2,
                                              char* Pb, unsigned pr4, int lane) {
  const h2 one2 = {(_Float16)1.f, (_Float16)1.f};
  unsigned fl = S.flu;
  h2 b = S.braw;
  if (fl & 0x1Eu) {                           // uniform: dependency within distance 2
    unsigned mN1 = 0u-((fl>>1)&1u), mP1 = 0u-((fl>>2)&1u);
    unsigned mN2 = 0u-((fl>>3)&1u), mP2 = 0u-((fl>>4)&1u);
    b = hmax2(b, u2h(h2u(up1) & mN1));
    b = hmax2(b, u2h(h2u(one2 - up1) & mP1));
    b = hmax2(b, u2h(h2u(up2) & mN2));
    b = hmax2(b, u2h(h2u(one2 - up2) & mP2));
  }
  h2 prev = S.prevraw;
  if (fl & 0x60u) {                           // uniform: head == recent head (rare)
    unsigned mR1 = 0u-((fl>>5)&1u), mR2 = 0u-((fl>>6)&1u), mRn = ~(mR1|mR2);
    prev = u2h((h2u(up1)&mR1) | (h2u(up2)&mR2) | (h2u(S.prevraw)&mRn));
  }
  unsigned ms = 0u-(fl&1u);
  unsigned hi = h2u(hmax2(prev, one2 - b));
  unsigned lo = h2u(hmin2(prev, b));
  h2 upd = u2h((hi&ms) | (lo&~ms));
  if ((lane & 39) == 0 && !(fl & 0x8000u))    // lanes 0,8,16,24: one per row-pair
    *(h2*)(Pb + S.ho + pr4) = upd;
  return upd;
}

__global__ __launch_bounds__(64, 2) void solve_kernel(
    const float* __restrict__ preds,
    const unsigned* __restrict__ ents,
    float* __restrict__ out) {
  __shared__ char Pb[LDSB];
  const int lane = threadIdx.x;
  // main-loop mapping: row-pair r2 = (lane>>3)&3, slot-lane g = (lane&7)|8*(lane>>5).
  // a slot group's 16 lanes split 8+8 across wave halves so each half-wave touches
  // 32 distinct banks (bank = 4*(atom&7) + r2) -> conflict-free slot reads.
  const unsigned pr4 = (unsigned)((lane >> 3) & 3) * 4u;
  const int g = (lane & 7) | ((lane >> 5) << 3);
  // staging mapping (independent of main loop)
  const int r2s = lane >> 4, cs = lane & 15;
  const size_t row0 = (size_t)blockIdx.x * ROWS;

  if (lane < 32) *(unsigned*)(Pb + ZOFF + lane*4) = 0u;                 // 8 zero atoms
  else           *(unsigned*)(Pb + OOFF + (lane-32)*4) = 0x3C003C00u;   // 8 one atoms

  // stage in: [atom][8 rows] fp16
  for (int i = 0; i < 16; ++i) {
    int a = i*32 + cs*2;
    float2 v0 = *(const float2*)(preds + (row0 + 2*r2s)     * NUM + a);
    float2 v1 = *(const float2*)(preds + (row0 + 2*r2s + 1) * NUM + a);
    h2 w0 = {(_Float16)v0.x, (_Float16)v1.x};
    h2 w1 = {(_Float16)v0.y, (_Float16)v1.y};
    *(h2*)(Pb + a*16 + r2s*4) = w0;
    *(h2*)(Pb + (a+1)*16 + r2s*4) = w1;
  }
  __syncthreads();

  // 4-deep pipeline: cons q->Ra, q+1->Rb, q+2->Rc, q+3->Rd.
  // reads(c) issued right after fin(c-3)  -> staleness window dist 1-2 (prep flags);
  // comb(c) consumes reads issued ~2 cons earlier (LDS latency hidden);
  // ldent(c) loaded 4 cons before use (L2/L3 latency hidden).
  ENT Ea = ldent(ents, 3, g), Eb = ldent(ents, 4, g);
  ENT Ec = ldent(ents, 5, g), Ed = ldent(ents, 6, g);
  RDv Ra, Rb, Rc, Rd; ST S;
  {
    ENT t0 = ldent(ents, 0, g), t1 = ldent(ents, 1, g), t2 = ldent(ents, 2, g);
    issue_reads(t0, Pb, pr4, Ra);
    issue_reads(t1, Pb, pr4, Rb);
    issue_reads(t2, Pb, pr4, Rc);
  }
  h2 up1 = (h2)0.0f, up2 = (h2)0.0f;

  #pragma unroll 1
  for (int q = 0; q < CONS; q += 4) {
    combine(Ra, ents, q, Pb, pr4, S);
    { h2 u = finalize(S, up1, up2, Pb, pr4, lane); up2 = up1; up1 = u; }   // c=q
    issue_reads(Ea, Pb, pr4, Rd);                                          // reads q+3
    Ea = ldent(ents, q+7, g);

    combine(Rb, ents, q+1, Pb, pr4, S);
    { h2 u = finalize(S, up1, up2, Pb, pr4, lane); up2 = up1; up1 = u; }   // c=q+1
    issue_reads(Eb, Pb, pr4, Ra);                                          // reads q+4
    Eb = ldent(ents, q+8, g);

    combine(Rc, ents, q+2, Pb, pr4, S);
    { h2 u = finalize(S, up1, up2, Pb, pr4, lane); up2 = up1; up1 = u; }   // c=q+2
    issue_reads(Ec, Pb, pr4, Rb);                                          // reads q+5
    Ec = ldent(ents, q+9, g);

    combine(Rd, ents, q+3, Pb, pr4, S);
    { h2 u = finalize(S, up1, up2, Pb, pr4, lane); up2 = up1; up1 = u; }   // c=q+3
    issue_reads(Ed, Pb, pr4, Rc);                                          // reads q+6
    Ed = ldent(ents, q+10, g);
  }

  __syncthreads();
  for (int i = 0; i < 16; ++i) {
    int a = i*32 + cs*2;
    h2 w0 = *(const h2*)(Pb + a*16 + r2s*4);
    h2 w1 = *(const h2*)(Pb + (a+1)*16 + r2s*4);
    float2 v0 = {(float)w0.x, (float)w1.x};
    float2 v1 = {(float)w0.y, (float)w1.y};
    *(float2*)(out + (row0 + 2*r2s)     * NUM + a) = v0;
    *(float2*)(out + (row0 + 2*r2s + 1) * NUM + a) = v1;
  }
}

extern "C" void kernel_launch(void* const* d_in, const int* in_sizes, int n_in,
                              void* d_out, int out_size, void* d_ws, size_t ws_size,
                              hipStream_t stream) {
  (void)in_sizes; (void)n_in; (void)out_size; (void)ws_size;
  const float* preds     = (const float*)d_in[0];
  const float* pos       = (const float*)d_in[1];
  const float* neg       = (const float*)d_in[2];
  const int*   head_atom = (const int*)d_in[3];
  const int*   head_sign = (const int*)d_in[4];

  unsigned* ents = (unsigned*)d_ws;      // NPAD * RSTR * 4 ≈ 175 KB

  prep_kernel<<<NPAD, 64, 0, stream>>>(pos, neg, head_atom, head_sign, ents);
  solve_kernel<<<BATCH / ROWS, 64, 0, stream>>>(preds, ents, (float*)d_out);
}